// Round 9
// baseline (700.749 us; speedup 1.0000x reference)
//
#include <hip/hip_runtime.h>

#define B_TOT 65536
#define RS 44            // padded row stride (floats) for h / t rows
#define KDET 4

// per-wave LDS scratch (no block-shared LDS; no __syncthreads in main)
#define SC_STRIDE 1584   // t_s [0,1056) (h1 time-shares [128,896)) | hA [1056,1584)
#define LDS_FLOATS (4*SC_STRIDE)   // 6336 floats = 25344 B

// workspace layout (float4 units)
#define WS_F   0         // 12*11*64 = 8448 float4
#define WS_W2  8448      // 16*64    = 1024 float4
#define WS_W3  9472      // 16*32    =  512 float4
#define WS_TOT 9984

// pair enumeration p=0..14 : (n,m) lexicographic n<m
__device__ const int PN_TAB[15] = {0,0,0,0,0,1,1,1,1,2,2,2,3,3,4};
__device__ const int PM_TAB[15] = {1,2,3,4,5,2,3,4,5,3,4,5,4,5,5};
// matchings -> 3 pair indices; sign alternates +,-,+,...
__device__ const int M1_TAB[15] = {0,0,0,1,1,1,2,2,2,3,3,3,4,4,4};
__device__ const int M2_TAB[15] = {9,10,11,6,7,8,5,7,8,5,6,8,5,6,7};
__device__ const int M3_TAB[15] = {14,13,12,14,13,12,14,11,10,13,11,9,12,10,9};

__device__ __forceinline__ float bcastf(float v, int l) {
    return __int_as_float(__builtin_amdgcn_readlane(__float_as_int(v), l));
}
// wave-local LDS ordering only; vmcnt NOT drained (keeps F/W loads in flight)
#define WFENCE() asm volatile("s_waitcnt lgkmcnt(0)" ::: "memory")

// prep: F~ swizzled [sk][c][d] float4 (cols 4c..4c+3 of row d), rows/cols >=41 zero;
// W2 packed [i4][lane]; W3 packed [i4][j2].
__global__ void prep_all(const float* __restrict__ dFud, const float* __restrict__ dFuu,
                         const float* __restrict__ dFdd, const float* __restrict__ Phf,
                         const float* __restrict__ W2, const float* __restrict__ W3,
                         float4* __restrict__ ws)
{
    int t = blockIdx.x * 256 + threadIdx.x;
    if (t < 12*11*64) {
        int d  = t & 63;
        int c  = (t >> 6) % 11;
        int sk = t / (11*64);
        int s = sk >> 2, k = sk & 3;
        const float* src = (s==0) ? dFuu : (s==1) ? dFdd : dFud;
        float v[4];
        #pragma unroll
        for (int j=0;j<4;j++){
            int e = 4*c + j;
            float r = 0.f;
            if (d < 41 && e < 41) {
                if (s < 2) r = 0.01f * (src[(k*41+d)*41+e] - src[(k*41+e)*41+d]);
                else     { r = 0.01f *  src[(k*41+d)*41+e]; if (k==0) r += Phf[d*41+e]; }
            }
            v[j] = r;
        }
        ws[WS_F + t] = make_float4(v[0],v[1],v[2],v[3]);
    } else if (t < 12*11*64 + 1024) {
        int u = t - 12*11*64;
        int i4 = u >> 6, j = u & 63;
        ws[WS_W2 + u] = make_float4(W2[(4*i4+0)*64 + j], W2[(4*i4+1)*64 + j],
                                    W2[(4*i4+2)*64 + j], W2[(4*i4+3)*64 + j]);
    } else if (t < WS_TOT) {
        int u = t - (12*11*64 + 1024);
        int i4 = u >> 5, j2 = u & 31;
        ws[WS_W3 + u] = make_float4(W3[(4*i4+0)*32 + j2], W3[(4*i4+1)*32 + j2],
                                    W3[(4*i4+2)*32 + j2], W3[(4*i4+3)*32 + j2]);
    }
}

// (256,4): VGPR cap 64 (empirical law: cap = 256/arg2), ~16 waves/CU.
// Body engineered to live within 64 VGPRs: F streamed one float4 at a time.
__global__ __launch_bounds__(256, 4)
void pfaff_main(const float* __restrict__ x, const int* __restrict__ spin,
                const float* __restrict__ se, const float* __restrict__ W1,
                const float* __restrict__ b1, const float* __restrict__ b2,
                const float* __restrict__ b3, const float* __restrict__ wdet,
                const float4* __restrict__ ws, float* __restrict__ out)
{
    __shared__ __align__(16) float lds[LDS_FLOATS];
    const int tid  = threadIdx.x;
    const int wave = tid >> 6, lane = tid & 63;
    float* sc  = lds + wave*SC_STRIDE;
    float* t_s = sc;            // [0,1056)
    float* h1  = sc + 128;      // [128,896) (time-shared with t_s)
    float* hA  = sc + 1056;     // [1056,1584)

    for (int i = lane; i < SC_STRIDE; i += 64) sc[i] = 0.f;
    WFENCE();

    const float4* wsF  = ws + WS_F;
    const float4* wsW2 = ws + WS_W2;
    const float4* wsW3 = ws + WS_W3;

    // ---- per-lane persistent preloads ----
    const float b1r = b1[lane];
    const float b2r = b2[lane];
    const float b3r = b3[lane & 31];
    const float w1c0 = W1[lane], w1c1 = W1[64 + lane];
    float emb0 = 0.f, emb1 = 0.f;
    #pragma unroll
    for (int j=0;j<8;j++){
        float wv = W1[(2+j)*64 + lane];
        emb0 = fmaf(wv, se[j],   emb0);
        emb1 = fmaf(wv, se[8+j], emb1);
    }
    int pn=0, pm=0, m1i=0, m2i=0, m3i=0;
    const int p = lane & 31, g = lane >> 5;
    if (p < 15) { pn=PN_TAB[p]; pm=PM_TAB[p];
                  m1i=M1_TAB[p]; m2i=M2_TAB[p]; m3i=M3_TAB[p]; }
    float wreg[4];
    #pragma unroll
    for (int k=0;k<4;k++) wreg[k] = wdet[k];
    const int le = (lane < 44) ? lane : 43;

    const int ebase = ((int)blockIdx.x * 4 + wave) * 8;
    #pragma unroll 1
    for (int pi = 0; pi < 4; ++pi) {
        const int e0 = ebase + pi*2;

        // ---- P0: particle data for 2 elements; Phi -> hA rows ----
        int s_n = 0; float xx = 0.f, xy = 0.f;
        if (lane < 12) {
            int gg = lane >= 6;
            int eg = e0 + gg;
            int n  = lane - gg*6;
            float2 xv = *(const float2*)(x + (size_t)(eg*6 + n)*2);
            xx = xv.x; xy = xv.y;
            s_n = spin[eg*6 + n];
        }
        unsigned long long bal = __ballot(lane < 12 && s_n == 1);
        const unsigned dn0 = (unsigned)bal & 63u;
        const unsigned dn1 = (unsigned)(bal >> 6) & 63u;

        if (lane < 12) {
            float ex = __expf(-0.5f*(xx*xx));
            float px0 = 0.7511255444649425f * ex;
            float px1 = 1.4142135623730951f * xx * px0;
            float px2 = fmaf(xx, px1, -0.7071067811865476f * px0);
            float ey = __expf(-0.5f*(xy*xy));
            float py0 = 0.7511255444649425f * ey;
            float py1 = 1.4142135623730951f * xy * py0;
            float py2 = fmaf(xy, py1, -0.7071067811865476f * py0);
            float* hr = hA + lane*RS;
            hr[0]=px0*py0; hr[1]=px0*py1; hr[2]=px0*py2;
            hr[3]=px1*py0; hr[4]=px1*py1; hr[5]=px1*py2;
            hr[6]=px2*py0; hr[7]=px2*py1; hr[8]=px2*py2;
            hr[41]=0.f; hr[42]=0.f; hr[43]=0.f;
        }

        // ---- L1 (10->64): registers via readlane; write h1 LDS ----
        #pragma unroll
        for (int r=0;r<12;r++){
            float xr = bcastf(xx, r);
            float yr = bcastf(xy, r);
            int   sr = __builtin_amdgcn_readlane(s_n, r);
            float a  = fmaf(xr, w1c0, b1r);
            a = fmaf(yr, w1c1, a);
            a += sr ? emb1 : emb0;
            h1[r*64 + lane] = __fdividef(a, 1.f + __expf(-a));
        }
        WFENCE();

        // ---- L2 (64->64): W2 via VMEM (coalesced), h via uniform LDS b128 ----
        float acc[12];
        #pragma unroll
        for (int r=0;r<12;r++) acc[r] = b2r;
        #pragma unroll
        for (int i4=0;i4<16;i4++){
            float4 w4 = wsW2[i4*64 + lane];
            #pragma unroll
            for (int r=0;r<12;r++){
                float4 h4 = *(const float4*)(h1 + r*64 + i4*4);
                acc[r]=fmaf(w4.x,h4.x,acc[r]); acc[r]=fmaf(w4.y,h4.y,acc[r]);
                acc[r]=fmaf(w4.z,h4.z,acc[r]); acc[r]=fmaf(w4.w,h4.w,acc[r]);
            }
        }
        WFENCE();
        #pragma unroll
        for (int r=0;r<12;r++){
            float v = acc[r];
            h1[r*64 + lane] = __fdividef(v, 1.f + __expf(-v));
        }
        WFENCE();

        // ---- L3 (64->32): half-wave per element; W3 via VMEM ----
        {
            int j2 = lane & 31, hf = lane >> 5;
            float a3[6];
            #pragma unroll
            for (int rr=0;rr<6;rr++) a3[rr] = b3r;
            #pragma unroll
            for (int i4=0;i4<16;i4++){
                float4 w4 = wsW3[i4*32 + j2];
                #pragma unroll
                for (int rr=0;rr<6;rr++){
                    float4 h4 = *(const float4*)(h1 + (hf*6+rr)*64 + i4*4);
                    a3[rr]=fmaf(w4.x,h4.x,a3[rr]); a3[rr]=fmaf(w4.y,h4.y,a3[rr]);
                    a3[rr]=fmaf(w4.z,h4.z,a3[rr]); a3[rr]=fmaf(w4.w,h4.w,a3[rr]);
                }
            }
            #pragma unroll
            for (int rr=0;rr<6;rr++) hA[(hf*6+rr)*RS + 9 + j2] = a3[rr];
        }
        WFENCE();

        // ---- h rows lane-distributed (lane = col), full 44 cols each ----
        float hreg[12];
        #pragma unroll
        for (int r=0;r<12;r++) hreg[r] = hA[r*RS + le];
        WFENCE();

        // ---- bilinear + pfaffian ----
        float total = 0.f;
        #pragma unroll 1
        for (int k = 0; k < KDET; ++k) {
            #pragma unroll 1
            for (int pass=0; pass<3; ++pass) {
                const float4* Fp = wsF + (size_t)(pass*4 + k)*(11*64) + lane;
                const unsigned mk0 = pass ? dn0 : ((~dn0) & 63u);
                const unsigned mk1 = pass ? dn1 : ((~dn1) & 63u);
                const unsigned act = mk0 | (mk1 << 6);   // bit u = gg*6+m active
                float tacc[12];
                #pragma unroll
                for (int u=0;u<12;u++) tacc[u] = 0.f;
                // stream F row one float4 at a time: live F regs = 4
                #pragma unroll
                for (int c=0;c<11;c++){
                    float4 f = Fp[c*64];
                    #pragma unroll
                    for (int u=0;u<12;u++){
                        if ((act>>u)&1) {
                            float hv = hreg[u];
                            tacc[u] = fmaf(f.x, bcastf(hv,4*c+0), tacc[u]);
                            tacc[u] = fmaf(f.y, bcastf(hv,4*c+1), tacc[u]);
                            tacc[u] = fmaf(f.z, bcastf(hv,4*c+2), tacc[u]);
                            tacc[u] = fmaf(f.w, bcastf(hv,4*c+3), tacc[u]);
                        }
                    }
                }
                const int dstb = (pass==2) ? 6 : 0;
                #pragma unroll
                for (int u=0;u<12;u++){
                    if ((act>>u)&1) {
                        int gg = u >= 6, m = u - gg*6;
                        int row = gg*12 + dstb + m;
                        if (lane < RS)
                            t_s[row*RS + lane] = (lane < 41) ? tacc[u] : 0.f;
                    }
                }
            }
            WFENCE();

            // ---- A[pair] for both elements: lanes (g*32+p), p<15 ----
            float av = 0.f;
            if (p < 15) {
                unsigned dng = g ? dn1 : dn0;
                int sn = (int)((dng>>pn)&1), sm = (int)((dng>>pm)&1);
                int hrow, trow; float sg;
                if (sn == sm)      { hrow = pn; trow = pm;     sg =  1.f; }
                else if (sn == 0)  { hrow = pn; trow = 6 + pm; sg =  1.f; }
                else               { hrow = pm; trow = 6 + pn; sg = -1.f; }
                const float4* hp = (const float4*)(hA  + (g*6  + hrow)*RS);
                const float4* tp = (const float4*)(t_s + (g*12 + trow)*RS);
                float a0=0.f,a1=0.f,a2=0.f,a3v=0.f;
                #pragma unroll
                for (int q=0;q<11;q++){
                    float4 hv = hp[q]; float4 tv = tp[q];
                    a0=fmaf(hv.x,tv.x,a0); a1=fmaf(hv.y,tv.y,a1);
                    a2=fmaf(hv.z,tv.z,a2); a3v=fmaf(hv.w,tv.w,a3v);
                }
                av = sg * ((a0+a1)+(a2+a3v));
            }
            int g32 = lane & 32;
            float q1 = __shfl(av, g32 + m1i);
            float q2 = __shfl(av, g32 + m2i);
            float q3 = __shfl(av, g32 + m3i);
            float term = 0.f;
            if (p < 15) { float pr = q1*q2*q3; term = (p & 1) ? -pr : pr; }
            term += __shfl_xor(term, 1);
            term += __shfl_xor(term, 2);
            term += __shfl_xor(term, 4);
            term += __shfl_xor(term, 8);
            total = fmaf(wreg[k], term, total);
            WFENCE();
        }

        if (p == 0) {
            int e = e0 + g;
            float sgn = (total > 0.f) ? 1.f : ((total < 0.f) ? -1.f : 1.f);
            out[e]         = sgn;
            out[B_TOT + e] = 0.5f * logf(fmaf(total, total, 1e-60f));
        }
        WFENCE();
    }
}

extern "C" void kernel_launch(void* const* d_in, const int* in_sizes, int n_in,
                              void* d_out, int out_size, void* d_ws, size_t ws_size,
                              hipStream_t stream)
{
    const float* x    = (const float*)d_in[0];
    const int*   spin = (const int*)  d_in[1];
    const float* se   = (const float*)d_in[2];
    const float* W1   = (const float*)d_in[3];
    const float* b1   = (const float*)d_in[4];
    const float* W2   = (const float*)d_in[5];
    const float* b2   = (const float*)d_in[6];
    const float* W3   = (const float*)d_in[7];
    const float* b3   = (const float*)d_in[8];
    const float* Phf  = (const float*)d_in[9];
    const float* dFud = (const float*)d_in[10];
    const float* dFuu = (const float*)d_in[11];
    const float* dFdd = (const float*)d_in[12];
    const float* w    = (const float*)d_in[13];
    float* out = (float*)d_out;
    float4* ws = (float4*)d_ws;

    hipLaunchKernelGGL(prep_all, dim3(39), dim3(256), 0, stream,
                       dFud, dFuu, dFdd, Phf, W2, W3, ws);
    hipLaunchKernelGGL(pfaff_main, dim3(2048), dim3(256), 0, stream,
                       x, spin, se, W1, b1, b2, b3, w, ws, out);
}

// Round 10
// 542.655 us; speedup vs baseline: 1.2913x; 1.2913x over previous
//
#include <hip/hip_runtime.h>

#define B_TOT 65536
#define RS 44            // padded row stride (floats) for h / t rows
#define KDET 4

// per-wave LDS scratch (no block-shared LDS; no __syncthreads in main)
#define SC_STRIDE 1584   // t_s [0,1056) (h1 time-shares [128,896)) | hA [1056,1584)
#define LDS_FLOATS (4*SC_STRIDE)   // 6336 floats = 25344 B

// workspace layout (float4 units)
#define WS_F   0         // 12*11*64 = 8448 float4
#define WS_W2  8448      // 16*64    = 1024 float4
#define WS_W3  9472      // 16*32    =  512 float4
#define WS_TOT 9984

// pair enumeration p=0..14 : (n,m) lexicographic n<m
__device__ const int PN_TAB[15] = {0,0,0,0,0,1,1,1,1,2,2,2,3,3,4};
__device__ const int PM_TAB[15] = {1,2,3,4,5,2,3,4,5,3,4,5,4,5,5};
// matchings -> 3 pair indices; sign alternates +,-,+,...
__device__ const int M1_TAB[15] = {0,0,0,1,1,1,2,2,2,3,3,3,4,4,4};
__device__ const int M2_TAB[15] = {9,10,11,6,7,8,5,7,8,5,6,8,5,6,7};
__device__ const int M3_TAB[15] = {14,13,12,14,13,12,14,11,10,13,11,9,12,10,9};

__device__ __forceinline__ float bcastf(float v, int l) {
    return __int_as_float(__builtin_amdgcn_readlane(__float_as_int(v), l));
}
// wave-local LDS ordering only; vmcnt NOT drained (keeps F/W loads in flight)
#define WFENCE() asm volatile("s_waitcnt lgkmcnt(0)" ::: "memory")

// prep: F~ swizzled [sk][c][d] float4 (cols 4c..4c+3 of row d), rows/cols >=41 zero;
// W2 packed [i4][lane]; W3 packed [i4][j2].
__global__ void prep_all(const float* __restrict__ dFud, const float* __restrict__ dFuu,
                         const float* __restrict__ dFdd, const float* __restrict__ Phf,
                         const float* __restrict__ W2, const float* __restrict__ W3,
                         float4* __restrict__ ws)
{
    int t = blockIdx.x * 256 + threadIdx.x;
    if (t < 12*11*64) {
        int d  = t & 63;
        int c  = (t >> 6) % 11;
        int sk = t / (11*64);
        int s = sk >> 2, k = sk & 3;
        const float* src = (s==0) ? dFuu : (s==1) ? dFdd : dFud;
        float v[4];
        #pragma unroll
        for (int j=0;j<4;j++){
            int e = 4*c + j;
            float r = 0.f;
            if (d < 41 && e < 41) {
                if (s < 2) r = 0.01f * (src[(k*41+d)*41+e] - src[(k*41+e)*41+d]);
                else     { r = 0.01f *  src[(k*41+d)*41+e]; if (k==0) r += Phf[d*41+e]; }
            }
            v[j] = r;
        }
        ws[WS_F + t] = make_float4(v[0],v[1],v[2],v[3]);
    } else if (t < 12*11*64 + 1024) {
        int u = t - 12*11*64;
        int i4 = u >> 6, j = u & 63;
        ws[WS_W2 + u] = make_float4(W2[(4*i4+0)*64 + j], W2[(4*i4+1)*64 + j],
                                    W2[(4*i4+2)*64 + j], W2[(4*i4+3)*64 + j]);
    } else if (t < WS_TOT) {
        int u = t - (12*11*64 + 1024);
        int i4 = u >> 5, j2 = u & 31;
        ws[WS_W3 + u] = make_float4(W3[(4*i4+0)*32 + j2], W3[(4*i4+1)*32 + j2],
                                    W3[(4*i4+2)*32 + j2], W3[(4*i4+3)*32 + j2]);
    }
}

// Empirical law on this toolchain: __launch_bounds__(B, N) => VGPR cap = 256/N
// AND residency cap N waves/SIMD. (256,3): cap ~85 VGPR (r7 body = 68, no
// spills) and 12 waves/CU (vs r7's 8).
__global__ __launch_bounds__(256, 3)
void pfaff_main(const float* __restrict__ x, const int* __restrict__ spin,
                const float* __restrict__ se, const float* __restrict__ W1,
                const float* __restrict__ b1, const float* __restrict__ b2,
                const float* __restrict__ b3, const float* __restrict__ wdet,
                const float4* __restrict__ ws, float* __restrict__ out)
{
    __shared__ __align__(16) float lds[LDS_FLOATS];
    const int tid  = threadIdx.x;
    const int wave = tid >> 6, lane = tid & 63;
    float* sc  = lds + wave*SC_STRIDE;
    float* t_s = sc;            // [0,1056)
    float* h1  = sc + 128;      // [128,896) (time-shared with t_s; L3 feed only)
    float* hA  = sc + 1056;     // [1056,1584)

    for (int i = lane; i < SC_STRIDE; i += 64) sc[i] = 0.f;
    WFENCE();

    const float4* wsF  = ws + WS_F;
    const float4* wsW2 = ws + WS_W2;
    const float4* wsW3 = ws + WS_W3;

    // ---- per-lane persistent preloads ----
    const float b1r = b1[lane];
    const float b2r = b2[lane];
    const float b3r = b3[lane & 31];
    const float w1c0 = W1[lane], w1c1 = W1[64 + lane];
    float emb0 = 0.f, emb1 = 0.f;
    #pragma unroll
    for (int j=0;j<8;j++){
        float wv = W1[(2+j)*64 + lane];
        emb0 = fmaf(wv, se[j],   emb0);
        emb1 = fmaf(wv, se[8+j], emb1);
    }
    int pn=0, pm=0, m1i=0, m2i=0, m3i=0;
    const int p = lane & 31, g = lane >> 5;
    if (p < 15) { pn=PN_TAB[p]; pm=PM_TAB[p];
                  m1i=M1_TAB[p]; m2i=M2_TAB[p]; m3i=M3_TAB[p]; }
    float wreg[4];
    #pragma unroll
    for (int k=0;k<4;k++) wreg[k] = wdet[k];
    const int le = (lane < 44) ? lane : 43;

    const int ebase = ((int)blockIdx.x * 4 + wave) * 8;
    #pragma unroll 1
    for (int pi = 0; pi < 4; ++pi) {
        const int e0 = ebase + pi*2;

        // ---- P0: particle data for 2 elements; Phi -> hA rows ----
        int s_n = 0; float xx = 0.f, xy = 0.f;
        if (lane < 12) {
            int gg = lane >= 6;
            int eg = e0 + gg;
            int n  = lane - gg*6;
            float2 xv = *(const float2*)(x + (size_t)(eg*6 + n)*2);
            xx = xv.x; xy = xv.y;
            s_n = spin[eg*6 + n];
        }
        unsigned long long bal = __ballot(lane < 12 && s_n == 1);
        const unsigned dn0 = (unsigned)bal & 63u;
        const unsigned dn1 = (unsigned)(bal >> 6) & 63u;

        if (lane < 12) {
            float ex = __expf(-0.5f*(xx*xx));
            float px0 = 0.7511255444649425f * ex;
            float px1 = 1.4142135623730951f * xx * px0;
            float px2 = fmaf(xx, px1, -0.7071067811865476f * px0);
            float ey = __expf(-0.5f*(xy*xy));
            float py0 = 0.7511255444649425f * ey;
            float py1 = 1.4142135623730951f * xy * py0;
            float py2 = fmaf(xy, py1, -0.7071067811865476f * py0);
            float* hr = hA + lane*RS;
            hr[0]=px0*py0; hr[1]=px0*py1; hr[2]=px0*py2;
            hr[3]=px1*py0; hr[4]=px1*py1; hr[5]=px1*py2;
            hr[6]=px2*py0; hr[7]=px2*py1; hr[8]=px2*py2;
            hr[41]=0.f; hr[42]=0.f; hr[43]=0.f;
        }

        // ---- L1 (10->64): pure registers, h1reg lane-distributed (lane=j) ----
        float h1reg[12];
        #pragma unroll
        for (int r=0;r<12;r++){
            float xr = bcastf(xx, r);
            float yr = bcastf(xy, r);
            int   sr = __builtin_amdgcn_readlane(s_n, r);
            float a  = fmaf(xr, w1c0, b1r);
            a = fmaf(yr, w1c1, a);
            a += sr ? emb1 : emb0;
            h1reg[r] = __fdividef(a, 1.f + __expf(-a));
        }

        // ---- L2 (64->64): per-lane W2T row (VMEM) x readlane(h1reg) ----
        float acc[12];
        #pragma unroll
        for (int r=0;r<12;r++) acc[r] = b2r;
        #pragma unroll
        for (int i4=0;i4<16;i4++){
            float4 w4 = wsW2[i4*64 + lane];
            #pragma unroll
            for (int r=0;r<12;r++){
                acc[r]=fmaf(w4.x, bcastf(h1reg[r],4*i4+0), acc[r]);
                acc[r]=fmaf(w4.y, bcastf(h1reg[r],4*i4+1), acc[r]);
                acc[r]=fmaf(w4.z, bcastf(h1reg[r],4*i4+2), acc[r]);
                acc[r]=fmaf(w4.w, bcastf(h1reg[r],4*i4+3), acc[r]);
            }
        }
        // h2 -> small LDS buffer (only consumer: L3's uniform float4 reads)
        #pragma unroll
        for (int r=0;r<12;r++){
            float v = acc[r];
            h1[r*64 + lane] = __fdividef(v, 1.f + __expf(-v));
        }
        WFENCE();

        // ---- L3 (64->32): half-wave per element; W3 via VMEM ----
        {
            int j2 = lane & 31, hf = lane >> 5;
            float a3[6];
            #pragma unroll
            for (int rr=0;rr<6;rr++) a3[rr] = b3r;
            #pragma unroll
            for (int i4=0;i4<16;i4++){
                float4 w4 = wsW3[i4*32 + j2];
                #pragma unroll
                for (int rr=0;rr<6;rr++){
                    float4 h4 = *(const float4*)(h1 + (hf*6+rr)*64 + i4*4);
                    a3[rr]=fmaf(w4.x,h4.x,a3[rr]); a3[rr]=fmaf(w4.y,h4.y,a3[rr]);
                    a3[rr]=fmaf(w4.z,h4.z,a3[rr]); a3[rr]=fmaf(w4.w,h4.w,a3[rr]);
                }
            }
            #pragma unroll
            for (int rr=0;rr<6;rr++) hA[(hf*6+rr)*RS + 9 + j2] = a3[rr];
        }
        WFENCE();

        // ---- h rows lane-distributed (lane = col) ----
        float hreg[12];
        #pragma unroll
        for (int r=0;r<12;r++) hreg[r] = hA[r*RS + le];
        WFENCE();

        // ---- bilinear + pfaffian (all-readlane matvec, full F row in regs) ----
        float total = 0.f;
        #pragma unroll 1
        for (int k = 0; k < KDET; ++k) {
            #pragma unroll 1
            for (int pass=0; pass<3; ++pass) {
                const float4* Fp = wsF + (size_t)(pass*4 + k)*(11*64) + lane;
                float4 fA=Fp[0],    fB=Fp[64],   fC=Fp[2*64], fD=Fp[3*64];
                float4 fE=Fp[4*64], fF=Fp[5*64], fG=Fp[6*64], fH=Fp[7*64];
                float4 fI=Fp[8*64], fJ=Fp[9*64], fK=Fp[10*64];
                const int dstb = (pass==2) ? 6 : 0;
                #pragma unroll
                for (int gg=0; gg<2; ++gg){
                    const unsigned dng = gg ? dn1 : dn0;
                    const unsigned mk  = pass ? dng : ((~dng) & 63u);
                    #pragma unroll
                    for (int m=0;m<6;m++){
                        if ((mk>>m)&1) {
                            const float hv = hreg[gg*6+m];
                            float a0, a1, a2, a3v;
                            a0  = fA.x * bcastf(hv,0);
                            a1  = fA.y * bcastf(hv,1);
                            a2  = fA.z * bcastf(hv,2);
                            a3v = fA.w * bcastf(hv,3);
                            a0  = fmaf(fB.x, bcastf(hv,4),  a0);
                            a1  = fmaf(fB.y, bcastf(hv,5),  a1);
                            a2  = fmaf(fB.z, bcastf(hv,6),  a2);
                            a3v = fmaf(fB.w, bcastf(hv,7),  a3v);
                            a0  = fmaf(fC.x, bcastf(hv,8),  a0);
                            a1  = fmaf(fC.y, bcastf(hv,9),  a1);
                            a2  = fmaf(fC.z, bcastf(hv,10), a2);
                            a3v = fmaf(fC.w, bcastf(hv,11), a3v);
                            a0  = fmaf(fD.x, bcastf(hv,12), a0);
                            a1  = fmaf(fD.y, bcastf(hv,13), a1);
                            a2  = fmaf(fD.z, bcastf(hv,14), a2);
                            a3v = fmaf(fD.w, bcastf(hv,15), a3v);
                            a0  = fmaf(fE.x, bcastf(hv,16), a0);
                            a1  = fmaf(fE.y, bcastf(hv,17), a1);
                            a2  = fmaf(fE.z, bcastf(hv,18), a2);
                            a3v = fmaf(fE.w, bcastf(hv,19), a3v);
                            a0  = fmaf(fF.x, bcastf(hv,20), a0);
                            a1  = fmaf(fF.y, bcastf(hv,21), a1);
                            a2  = fmaf(fF.z, bcastf(hv,22), a2);
                            a3v = fmaf(fF.w, bcastf(hv,23), a3v);
                            a0  = fmaf(fG.x, bcastf(hv,24), a0);
                            a1  = fmaf(fG.y, bcastf(hv,25), a1);
                            a2  = fmaf(fG.z, bcastf(hv,26), a2);
                            a3v = fmaf(fG.w, bcastf(hv,27), a3v);
                            a0  = fmaf(fH.x, bcastf(hv,28), a0);
                            a1  = fmaf(fH.y, bcastf(hv,29), a1);
                            a2  = fmaf(fH.z, bcastf(hv,30), a2);
                            a3v = fmaf(fH.w, bcastf(hv,31), a3v);
                            a0  = fmaf(fI.x, bcastf(hv,32), a0);
                            a1  = fmaf(fI.y, bcastf(hv,33), a1);
                            a2  = fmaf(fI.z, bcastf(hv,34), a2);
                            a3v = fmaf(fI.w, bcastf(hv,35), a3v);
                            a0  = fmaf(fJ.x, bcastf(hv,36), a0);
                            a1  = fmaf(fJ.y, bcastf(hv,37), a1);
                            a2  = fmaf(fJ.z, bcastf(hv,38), a2);
                            a3v = fmaf(fJ.w, bcastf(hv,39), a3v);
                            a0  = fmaf(fK.x, bcastf(hv,40), a0);
                            float t = (a0+a1)+(a2+a3v);
                            if (lane < RS)
                                t_s[(gg*12 + dstb + m)*RS + lane] = (lane < 41) ? t : 0.f;
                        }
                    }
                }
            }
            WFENCE();

            // ---- A[pair] for both elements: lanes (g*32+p), p<15 ----
            float av = 0.f;
            if (p < 15) {
                unsigned dng = g ? dn1 : dn0;
                int sn = (int)((dng>>pn)&1), sm = (int)((dng>>pm)&1);
                int hrow, trow; float sg;
                if (sn == sm)      { hrow = pn; trow = pm;     sg =  1.f; }
                else if (sn == 0)  { hrow = pn; trow = 6 + pm; sg =  1.f; }
                else               { hrow = pm; trow = 6 + pn; sg = -1.f; }
                const float4* hp = (const float4*)(hA  + (g*6  + hrow)*RS);
                const float4* tp = (const float4*)(t_s + (g*12 + trow)*RS);
                float a0=0.f,a1=0.f,a2=0.f,a3v=0.f;
                #pragma unroll
                for (int q=0;q<11;q++){
                    float4 hv = hp[q]; float4 tv = tp[q];
                    a0=fmaf(hv.x,tv.x,a0); a1=fmaf(hv.y,tv.y,a1);
                    a2=fmaf(hv.z,tv.z,a2); a3v=fmaf(hv.w,tv.w,a3v);
                }
                av = sg * ((a0+a1)+(a2+a3v));
            }
            int g32 = lane & 32;
            float q1 = __shfl(av, g32 + m1i);
            float q2 = __shfl(av, g32 + m2i);
            float q3 = __shfl(av, g32 + m3i);
            float term = 0.f;
            if (p < 15) { float pr = q1*q2*q3; term = (p & 1) ? -pr : pr; }
            term += __shfl_xor(term, 1);
            term += __shfl_xor(term, 2);
            term += __shfl_xor(term, 4);
            term += __shfl_xor(term, 8);
            total = fmaf(wreg[k], term, total);
            WFENCE();
        }

        if (p == 0) {
            int e = e0 + g;
            float sgn = (total > 0.f) ? 1.f : ((total < 0.f) ? -1.f : 1.f);
            out[e]         = sgn;
            out[B_TOT + e] = 0.5f * logf(fmaf(total, total, 1e-60f));
        }
        WFENCE();
    }
}

extern "C" void kernel_launch(void* const* d_in, const int* in_sizes, int n_in,
                              void* d_out, int out_size, void* d_ws, size_t ws_size,
                              hipStream_t stream)
{
    const float* x    = (const float*)d_in[0];
    const int*   spin = (const int*)  d_in[1];
    const float* se   = (const float*)d_in[2];
    const float* W1   = (const float*)d_in[3];
    const float* b1   = (const float*)d_in[4];
    const float* W2   = (const float*)d_in[5];
    const float* b2   = (const float*)d_in[6];
    const float* W3   = (const float*)d_in[7];
    const float* b3   = (const float*)d_in[8];
    const float* Phf  = (const float*)d_in[9];
    const float* dFud = (const float*)d_in[10];
    const float* dFuu = (const float*)d_in[11];
    const float* dFdd = (const float*)d_in[12];
    const float* w    = (const float*)d_in[13];
    float* out = (float*)d_out;
    float4* ws = (float4*)d_ws;

    hipLaunchKernelGGL(prep_all, dim3(39), dim3(256), 0, stream,
                       dFud, dFuu, dFdd, Phf, W2, W3, ws);
    hipLaunchKernelGGL(pfaff_main, dim3(2048), dim3(256), 0, stream,
                       x, spin, se, W1, b1, b2, b3, w, ws, out);
}

// Round 11
// 538.414 us; speedup vs baseline: 1.3015x; 1.0079x over previous
//
#include <hip/hip_runtime.h>

#define B_TOT 65536
#define RS 44            // padded row stride (floats) for h / t rows
#define KDET 4

// ---- LDS: block-shared weights + per-wave scratch (one __syncthreads at init)
#define OFF_W2T  0                   // 64*68 = 4352 (W2^T, rows padded to 68)
#define OFF_W3T  4352                // 32*68 = 2176
#define OFF_SC   6528                // 4 waves * 1584
#define SC_STRIDE 1584               // t_s [0,1056) (h1 time-shares [128,896)) | hA [1056,1584)
#define LDS_FLOATS (6528 + 4*1584)   // 12864 floats = 51456 B -> 3 blocks/CU

// workspace layout (float4 units): F only
#define WS_F   0                     // 12*11*64 = 8448 float4 = 135168 B

// pair enumeration p=0..14 : (n,m) lexicographic n<m
__device__ const int PN_TAB[15] = {0,0,0,0,0,1,1,1,1,2,2,2,3,3,4};
__device__ const int PM_TAB[15] = {1,2,3,4,5,2,3,4,5,3,4,5,4,5,5};
// matchings -> 3 pair indices; sign alternates +,-,+,...
__device__ const int M1_TAB[15] = {0,0,0,1,1,1,2,2,2,3,3,3,4,4,4};
__device__ const int M2_TAB[15] = {9,10,11,6,7,8,5,7,8,5,6,8,5,6,7};
__device__ const int M3_TAB[15] = {14,13,12,14,13,12,14,11,10,13,11,9,12,10,9};

__device__ __forceinline__ float bcastf(float v, int l) {
    return __int_as_float(__builtin_amdgcn_readlane(__float_as_int(v), l));
}
// wave-local LDS ordering only; vmcnt NOT drained (keeps F loads in flight)
#define WFENCE() asm volatile("s_waitcnt lgkmcnt(0)" ::: "memory")

// prep: F~ swizzled [sk][c][d] float4 (cols 4c..4c+3 of row d), rows/cols >=41 zero
__global__ void prep_F(const float* __restrict__ dFud, const float* __restrict__ dFuu,
                       const float* __restrict__ dFdd, const float* __restrict__ Phf,
                       float4* __restrict__ ws)
{
    int t = blockIdx.x * 256 + threadIdx.x;
    if (t >= 12*11*64) return;
    int d  = t & 63;
    int c  = (t >> 6) % 11;
    int sk = t / (11*64);
    int s = sk >> 2, k = sk & 3;
    const float* src = (s==0) ? dFuu : (s==1) ? dFdd : dFud;
    float v[4];
    #pragma unroll
    for (int j=0;j<4;j++){
        int e = 4*c + j;
        float r = 0.f;
        if (d < 41 && e < 41) {
            if (s < 2) r = 0.01f * (src[(k*41+d)*41+e] - src[(k*41+e)*41+d]);
            else     { r = 0.01f *  src[(k*41+d)*41+e]; if (k==0) r += Phf[d*41+e]; }
        }
        v[j] = r;
    }
    ws[WS_F + t] = make_float4(v[0],v[1],v[2],v[3]);
}

// Empirical laws (this toolchain): __launch_bounds__(B,N) => VGPR cap = 256/N
// AND residency cap N waves/SIMD. (256,3): cap 85 (body compiles ~68-84,
// spill-free like r7), 12 waves/CU; LDS 51.5KB -> 3 blocks/CU matches exactly.
__global__ __launch_bounds__(256, 3)
void pfaff_main(const float* __restrict__ x, const int* __restrict__ spin,
                const float* __restrict__ se, const float* __restrict__ W1,
                const float* __restrict__ b1, const float* __restrict__ W2,
                const float* __restrict__ b2, const float* __restrict__ W3,
                const float* __restrict__ b3, const float* __restrict__ wdet,
                const float4* __restrict__ ws, float* __restrict__ out)
{
    __shared__ __align__(16) float lds[LDS_FLOATS];
    float* W2tl = lds + OFF_W2T;
    float* W3tl = lds + OFF_W3T;

    const int tid  = threadIdx.x;
    const int wave = tid >> 6, lane = tid & 63;

    // ---- stage W2^T / W3^T into LDS (pad-68 rows, pads zeroed) ----
    for (int idx = tid; idx < 64*68; idx += 256) {
        int j = idx / 68, i = idx - j*68;
        W2tl[idx] = (i < 64) ? W2[i*64 + j] : 0.f;
    }
    for (int idx = tid; idx < 32*68; idx += 256) {
        int j = idx / 68, i = idx - j*68;
        W3tl[idx] = (i < 64) ? W3[i*32 + j] : 0.f;
    }
    float* sc  = lds + OFF_SC + wave*SC_STRIDE;
    float* t_s = sc;            // [0,1056)
    float* h1  = sc + 128;      // [128,896) (time-shared with t_s; L3 feed only)
    float* hA  = sc + 1056;     // [1056,1584)
    for (int i = lane; i < SC_STRIDE; i += 64) sc[i] = 0.f;
    __syncthreads();            // once; waves independent afterwards

    const float4* wsF = ws + WS_F;

    // ---- per-lane persistent preloads (from global; tiny, one-time) ----
    const float b1r = b1[lane];
    const float b2r = b2[lane];
    const float b3r = b3[lane & 31];
    const float w1c0 = W1[lane], w1c1 = W1[64 + lane];
    float emb0 = 0.f, emb1 = 0.f;
    #pragma unroll
    for (int j=0;j<8;j++){
        float wv = W1[(2+j)*64 + lane];
        emb0 = fmaf(wv, se[j],   emb0);
        emb1 = fmaf(wv, se[8+j], emb1);
    }
    int pn=0, pm=0, m1i=0, m2i=0, m3i=0;
    const int p = lane & 31, g = lane >> 5;
    if (p < 15) { pn=PN_TAB[p]; pm=PM_TAB[p];
                  m1i=M1_TAB[p]; m2i=M2_TAB[p]; m3i=M3_TAB[p]; }
    float wreg[4];
    #pragma unroll
    for (int k=0;k<4;k++) wreg[k] = wdet[k];
    const int le = (lane < 44) ? lane : 43;

    const int ebase = ((int)blockIdx.x * 4 + wave) * 8;
    #pragma unroll 1
    for (int pi = 0; pi < 4; ++pi) {
        const int e0 = ebase + pi*2;

        // ---- P0: particle data for 2 elements; Phi -> hA rows ----
        int s_n = 0; float xx = 0.f, xy = 0.f;
        if (lane < 12) {
            int gg = lane >= 6;
            int eg = e0 + gg;
            int n  = lane - gg*6;
            float2 xv = *(const float2*)(x + (size_t)(eg*6 + n)*2);
            xx = xv.x; xy = xv.y;
            s_n = spin[eg*6 + n];
        }
        unsigned long long bal = __ballot(lane < 12 && s_n == 1);
        const unsigned dn0 = (unsigned)bal & 63u;
        const unsigned dn1 = (unsigned)(bal >> 6) & 63u;

        if (lane < 12) {
            float ex = __expf(-0.5f*(xx*xx));
            float px0 = 0.7511255444649425f * ex;
            float px1 = 1.4142135623730951f * xx * px0;
            float px2 = fmaf(xx, px1, -0.7071067811865476f * px0);
            float ey = __expf(-0.5f*(xy*xy));
            float py0 = 0.7511255444649425f * ey;
            float py1 = 1.4142135623730951f * xy * py0;
            float py2 = fmaf(xy, py1, -0.7071067811865476f * py0);
            float* hr = hA + lane*RS;
            hr[0]=px0*py0; hr[1]=px0*py1; hr[2]=px0*py2;
            hr[3]=px1*py0; hr[4]=px1*py1; hr[5]=px1*py2;
            hr[6]=px2*py0; hr[7]=px2*py1; hr[8]=px2*py2;
            hr[41]=0.f; hr[42]=0.f; hr[43]=0.f;
        }

        // ---- L1 (10->64): pure registers, h1reg lane-distributed (lane=j) ----
        float h1reg[12];
        #pragma unroll
        for (int r=0;r<12;r++){
            float xr = bcastf(xx, r);
            float yr = bcastf(xy, r);
            int   sr = __builtin_amdgcn_readlane(s_n, r);
            float a  = fmaf(xr, w1c0, b1r);
            a = fmaf(yr, w1c1, a);
            a += sr ? emb1 : emb0;
            h1reg[r] = __fdividef(a, 1.f + __expf(-a));
        }

        // ---- L2 (64->64): per-lane W2T row (LDS) x readlane(h1reg) ----
        float acc[12];
        #pragma unroll
        for (int r=0;r<12;r++) acc[r] = b2r;
        #pragma unroll
        for (int i4=0;i4<16;i4++){
            float4 w4 = *(const float4*)(W2tl + lane*68 + i4*4);
            #pragma unroll
            for (int r=0;r<12;r++){
                acc[r]=fmaf(w4.x, bcastf(h1reg[r],4*i4+0), acc[r]);
                acc[r]=fmaf(w4.y, bcastf(h1reg[r],4*i4+1), acc[r]);
                acc[r]=fmaf(w4.z, bcastf(h1reg[r],4*i4+2), acc[r]);
                acc[r]=fmaf(w4.w, bcastf(h1reg[r],4*i4+3), acc[r]);
            }
        }
        // h2 -> small LDS buffer (only consumer: L3's float4 reads)
        #pragma unroll
        for (int r=0;r<12;r++){
            float v = acc[r];
            h1[r*64 + lane] = __fdividef(v, 1.f + __expf(-v));
        }
        WFENCE();

        // ---- L3 (64->32): half-wave per element; W3T from LDS ----
        {
            int j2 = lane & 31, hf = lane >> 5;
            float a3[6];
            #pragma unroll
            for (int rr=0;rr<6;rr++) a3[rr] = b3r;
            #pragma unroll
            for (int i4=0;i4<16;i4++){
                float4 w4 = *(const float4*)(W3tl + j2*68 + i4*4);
                #pragma unroll
                for (int rr=0;rr<6;rr++){
                    float4 h4 = *(const float4*)(h1 + (hf*6+rr)*64 + i4*4);
                    a3[rr]=fmaf(w4.x,h4.x,a3[rr]); a3[rr]=fmaf(w4.y,h4.y,a3[rr]);
                    a3[rr]=fmaf(w4.z,h4.z,a3[rr]); a3[rr]=fmaf(w4.w,h4.w,a3[rr]);
                }
            }
            #pragma unroll
            for (int rr=0;rr<6;rr++) hA[(hf*6+rr)*RS + 9 + j2] = a3[rr];
        }
        WFENCE();

        // ---- h rows lane-distributed (lane = col) ----
        float hreg[12];
        #pragma unroll
        for (int r=0;r<12;r++) hreg[r] = hA[r*RS + le];
        WFENCE();

        // ---- bilinear + pfaffian (all-readlane matvec, full F row in regs) ----
        float total = 0.f;
        #pragma unroll 1
        for (int k = 0; k < KDET; ++k) {
            #pragma unroll 1
            for (int pass=0; pass<3; ++pass) {
                const float4* Fp = wsF + (size_t)(pass*4 + k)*(11*64) + lane;
                float4 fA=Fp[0],    fB=Fp[64],   fC=Fp[2*64], fD=Fp[3*64];
                float4 fE=Fp[4*64], fF=Fp[5*64], fG=Fp[6*64], fH=Fp[7*64];
                float4 fI=Fp[8*64], fJ=Fp[9*64], fK=Fp[10*64];
                const int dstb = (pass==2) ? 6 : 0;
                #pragma unroll
                for (int gg=0; gg<2; ++gg){
                    const unsigned dng = gg ? dn1 : dn0;
                    const unsigned mk  = pass ? dng : ((~dng) & 63u);
                    #pragma unroll
                    for (int m=0;m<6;m++){
                        if ((mk>>m)&1) {
                            const float hv = hreg[gg*6+m];
                            float a0, a1, a2, a3v;
                            a0  = fA.x * bcastf(hv,0);
                            a1  = fA.y * bcastf(hv,1);
                            a2  = fA.z * bcastf(hv,2);
                            a3v = fA.w * bcastf(hv,3);
                            a0  = fmaf(fB.x, bcastf(hv,4),  a0);
                            a1  = fmaf(fB.y, bcastf(hv,5),  a1);
                            a2  = fmaf(fB.z, bcastf(hv,6),  a2);
                            a3v = fmaf(fB.w, bcastf(hv,7),  a3v);
                            a0  = fmaf(fC.x, bcastf(hv,8),  a0);
                            a1  = fmaf(fC.y, bcastf(hv,9),  a1);
                            a2  = fmaf(fC.z, bcastf(hv,10), a2);
                            a3v = fmaf(fC.w, bcastf(hv,11), a3v);
                            a0  = fmaf(fD.x, bcastf(hv,12), a0);
                            a1  = fmaf(fD.y, bcastf(hv,13), a1);
                            a2  = fmaf(fD.z, bcastf(hv,14), a2);
                            a3v = fmaf(fD.w, bcastf(hv,15), a3v);
                            a0  = fmaf(fE.x, bcastf(hv,16), a0);
                            a1  = fmaf(fE.y, bcastf(hv,17), a1);
                            a2  = fmaf(fE.z, bcastf(hv,18), a2);
                            a3v = fmaf(fE.w, bcastf(hv,19), a3v);
                            a0  = fmaf(fF.x, bcastf(hv,20), a0);
                            a1  = fmaf(fF.y, bcastf(hv,21), a1);
                            a2  = fmaf(fF.z, bcastf(hv,22), a2);
                            a3v = fmaf(fF.w, bcastf(hv,23), a3v);
                            a0  = fmaf(fG.x, bcastf(hv,24), a0);
                            a1  = fmaf(fG.y, bcastf(hv,25), a1);
                            a2  = fmaf(fG.z, bcastf(hv,26), a2);
                            a3v = fmaf(fG.w, bcastf(hv,27), a3v);
                            a0  = fmaf(fH.x, bcastf(hv,28), a0);
                            a1  = fmaf(fH.y, bcastf(hv,29), a1);
                            a2  = fmaf(fH.z, bcastf(hv,30), a2);
                            a3v = fmaf(fH.w, bcastf(hv,31), a3v);
                            a0  = fmaf(fI.x, bcastf(hv,32), a0);
                            a1  = fmaf(fI.y, bcastf(hv,33), a1);
                            a2  = fmaf(fI.z, bcastf(hv,34), a2);
                            a3v = fmaf(fI.w, bcastf(hv,35), a3v);
                            a0  = fmaf(fJ.x, bcastf(hv,36), a0);
                            a1  = fmaf(fJ.y, bcastf(hv,37), a1);
                            a2  = fmaf(fJ.z, bcastf(hv,38), a2);
                            a3v = fmaf(fJ.w, bcastf(hv,39), a3v);
                            a0  = fmaf(fK.x, bcastf(hv,40), a0);
                            float t = (a0+a1)+(a2+a3v);
                            if (lane < RS)
                                t_s[(gg*12 + dstb + m)*RS + lane] = (lane < 41) ? t : 0.f;
                        }
                    }
                }
            }
            WFENCE();

            // ---- A[pair] for both elements: lanes (g*32+p), p<15 ----
            float av = 0.f;
            if (p < 15) {
                unsigned dng = g ? dn1 : dn0;
                int sn = (int)((dng>>pn)&1), sm = (int)((dng>>pm)&1);
                int hrow, trow; float sg;
                if (sn == sm)      { hrow = pn; trow = pm;     sg =  1.f; }
                else if (sn == 0)  { hrow = pn; trow = 6 + pm; sg =  1.f; }
                else               { hrow = pm; trow = 6 + pn; sg = -1.f; }
                const float4* hp = (const float4*)(hA  + (g*6  + hrow)*RS);
                const float4* tp = (const float4*)(t_s + (g*12 + trow)*RS);
                float a0=0.f,a1=0.f,a2=0.f,a3v=0.f;
                #pragma unroll
                for (int q=0;q<11;q++){
                    float4 hv = hp[q]; float4 tv = tp[q];
                    a0=fmaf(hv.x,tv.x,a0); a1=fmaf(hv.y,tv.y,a1);
                    a2=fmaf(hv.z,tv.z,a2); a3v=fmaf(hv.w,tv.w,a3v);
                }
                av = sg * ((a0+a1)+(a2+a3v));
            }
            int g32 = lane & 32;
            float q1 = __shfl(av, g32 + m1i);
            float q2 = __shfl(av, g32 + m2i);
            float q3 = __shfl(av, g32 + m3i);
            float term = 0.f;
            if (p < 15) { float pr = q1*q2*q3; term = (p & 1) ? -pr : pr; }
            term += __shfl_xor(term, 1);
            term += __shfl_xor(term, 2);
            term += __shfl_xor(term, 4);
            term += __shfl_xor(term, 8);
            total = fmaf(wreg[k], term, total);
            WFENCE();
        }

        if (p == 0) {
            int e = e0 + g;
            float sgn = (total > 0.f) ? 1.f : ((total < 0.f) ? -1.f : 1.f);
            out[e]         = sgn;
            out[B_TOT + e] = 0.5f * logf(fmaf(total, total, 1e-60f));
        }
        WFENCE();
    }
}

extern "C" void kernel_launch(void* const* d_in, const int* in_sizes, int n_in,
                              void* d_out, int out_size, void* d_ws, size_t ws_size,
                              hipStream_t stream)
{
    const float* x    = (const float*)d_in[0];
    const int*   spin = (const int*)  d_in[1];
    const float* se   = (const float*)d_in[2];
    const float* W1   = (const float*)d_in[3];
    const float* b1   = (const float*)d_in[4];
    const float* W2   = (const float*)d_in[5];
    const float* b2   = (const float*)d_in[6];
    const float* W3   = (const float*)d_in[7];
    const float* b3   = (const float*)d_in[8];
    const float* Phf  = (const float*)d_in[9];
    const float* dFud = (const float*)d_in[10];
    const float* dFuu = (const float*)d_in[11];
    const float* dFdd = (const float*)d_in[12];
    const float* w    = (const float*)d_in[13];
    float* out = (float*)d_out;
    float4* ws = (float4*)d_ws;

    hipLaunchKernelGGL(prep_F, dim3(33), dim3(256), 0, stream,
                       dFud, dFuu, dFdd, Phf, ws);
    hipLaunchKernelGGL(pfaff_main, dim3(2048), dim3(256), 0, stream,
                       x, spin, se, W1, b1, W2, b2, W3, b3, w, ws, out);
}

// Round 12
// 488.062 us; speedup vs baseline: 1.4358x; 1.1032x over previous
//
#include <hip/hip_runtime.h>

#define B_TOT 65536
#define RS 44            // padded row stride (floats) for h / t rows
#define KDET 4

// ---- LDS: block-shared weights + per-wave scratch (one __syncthreads at init)
#define OFF_W2T  0                   // 64*68 = 4352 (W2^T, rows padded to 68)
#define OFF_W3T  4352                // 32*68 = 2176
#define OFF_SC   6528                // 4 waves * 1584
#define SC_STRIDE 1584               // t_s [0,1056) (h1 time-shares [128,896)) | hA [1056,1584)
#define LDS_FLOATS (6528 + 4*1584)   // 12864 floats = 51456 B -> 3 blocks/CU

// workspace layout (float4 units): F only
#define WS_F   0                     // 12*11*64 = 8448 float4 = 135168 B

// pair enumeration p=0..14 : (n,m) lexicographic n<m
__device__ const int PN_TAB[15] = {0,0,0,0,0,1,1,1,1,2,2,2,3,3,4};
__device__ const int PM_TAB[15] = {1,2,3,4,5,2,3,4,5,3,4,5,4,5,5};
// matchings -> 3 pair indices; sign alternates +,-,+,...
__device__ const int M1_TAB[15] = {0,0,0,1,1,1,2,2,2,3,3,3,4,4,4};
__device__ const int M2_TAB[15] = {9,10,11,6,7,8,5,7,8,5,6,8,5,6,7};
__device__ const int M3_TAB[15] = {14,13,12,14,13,12,14,11,10,13,11,9,12,10,9};

__device__ __forceinline__ float bcastf(float v, int l) {
    return __int_as_float(__builtin_amdgcn_readlane(__float_as_int(v), l));
}
// wave-local LDS ordering only; vmcnt NOT drained (keeps F loads in flight)
#define WFENCE() asm volatile("s_waitcnt lgkmcnt(0)" ::: "memory")

// prep: F~ swizzled [sk][c][d] float4 (cols 4c..4c+3 of row d), rows/cols >=41 zero
__global__ void prep_F(const float* __restrict__ dFud, const float* __restrict__ dFuu,
                       const float* __restrict__ dFdd, const float* __restrict__ Phf,
                       float4* __restrict__ ws)
{
    int t = blockIdx.x * 256 + threadIdx.x;
    if (t >= 12*11*64) return;
    int d  = t & 63;
    int c  = (t >> 6) % 11;
    int sk = t / (11*64);
    int s = sk >> 2, k = sk & 3;
    const float* src = (s==0) ? dFuu : (s==1) ? dFdd : dFud;
    float v[4];
    #pragma unroll
    for (int j=0;j<4;j++){
        int e = 4*c + j;
        float r = 0.f;
        if (d < 41 && e < 41) {
            if (s < 2) r = 0.01f * (src[(k*41+d)*41+e] - src[(k*41+e)*41+d]);
            else     { r = 0.01f *  src[(k*41+d)*41+e]; if (k==0) r += Phf[d*41+e]; }
        }
        v[j] = r;
    }
    ws[WS_F + t] = make_float4(v[0],v[1],v[2],v[3]);
}

// (256,3): VGPR cap 85, 12 waves/CU; LDS 51.5KB -> 3 blocks/CU matches.
__global__ __launch_bounds__(256, 3)
void pfaff_main(const float* __restrict__ x, const int* __restrict__ spin,
                const float* __restrict__ se, const float* __restrict__ W1,
                const float* __restrict__ b1, const float* __restrict__ W2,
                const float* __restrict__ b2, const float* __restrict__ W3,
                const float* __restrict__ b3, const float* __restrict__ wdet,
                const float4* __restrict__ ws, float* __restrict__ out)
{
    __shared__ __align__(16) float lds[LDS_FLOATS];
    float* W2tl = lds + OFF_W2T;
    float* W3tl = lds + OFF_W3T;

    const int tid  = threadIdx.x;
    const int wave = tid >> 6, lane = tid & 63;

    // ---- stage W2^T / W3^T into LDS (pad-68 rows, pads zeroed) ----
    for (int idx = tid; idx < 64*68; idx += 256) {
        int j = idx / 68, i = idx - j*68;
        W2tl[idx] = (i < 64) ? W2[i*64 + j] : 0.f;
    }
    for (int idx = tid; idx < 32*68; idx += 256) {
        int j = idx / 68, i = idx - j*68;
        W3tl[idx] = (i < 64) ? W3[i*32 + j] : 0.f;
    }
    float* sc  = lds + OFF_SC + wave*SC_STRIDE;
    float* t_s = sc;            // [0,1056)
    float* h1  = sc + 128;      // [128,896) (time-shared with t_s)
    float* hA  = sc + 1056;     // [1056,1584)
    for (int i = lane; i < SC_STRIDE; i += 64) sc[i] = 0.f;
    __syncthreads();            // once; waves independent afterwards

    const float4* wsF = ws + WS_F;

    // ---- per-lane persistent preloads (from global; tiny, one-time) ----
    const float b1r = b1[lane];
    const float b2r = b2[lane];
    const float b3r = b3[lane & 31];
    const float w1c0 = W1[lane], w1c1 = W1[64 + lane];
    float emb0 = 0.f, emb1 = 0.f;
    #pragma unroll
    for (int j=0;j<8;j++){
        float wv = W1[(2+j)*64 + lane];
        emb0 = fmaf(wv, se[j],   emb0);
        emb1 = fmaf(wv, se[8+j], emb1);
    }
    int pn=0, pm=0, m1i=0, m2i=0, m3i=0;
    const int p = lane & 31, g = lane >> 5;
    if (p < 15) { pn=PN_TAB[p]; pm=PM_TAB[p];
                  m1i=M1_TAB[p]; m2i=M2_TAB[p]; m3i=M3_TAB[p]; }
    float wreg[4];
    #pragma unroll
    for (int k=0;k<4;k++) wreg[k] = wdet[k];
    const int le = (lane < 44) ? lane : 43;

    const int ebase = ((int)blockIdx.x * 4 + wave) * 8;
    #pragma unroll 1
    for (int pi = 0; pi < 4; ++pi) {
        const int e0 = ebase + pi*2;

        // ---- P0: particle data for 2 elements; Phi -> hA rows ----
        int s_n = 0; float xx = 0.f, xy = 0.f;
        if (lane < 12) {
            int gg = lane >= 6;
            int eg = e0 + gg;
            int n  = lane - gg*6;
            float2 xv = *(const float2*)(x + (size_t)(eg*6 + n)*2);
            xx = xv.x; xy = xv.y;
            s_n = spin[eg*6 + n];
        }
        unsigned long long bal = __ballot(lane < 12 && s_n == 1);
        // FORCE the masks into SGPRs: per-m conditions must be scalar branches,
        // not exec-masked (if-converted) execution of all 12 matvecs.
        const unsigned dn0 = (unsigned)__builtin_amdgcn_readfirstlane((int)((unsigned)bal & 63u));
        const unsigned dn1 = (unsigned)__builtin_amdgcn_readfirstlane((int)((unsigned)(bal >> 6) & 63u));

        if (lane < 12) {
            float ex = __expf(-0.5f*(xx*xx));
            float px0 = 0.7511255444649425f * ex;
            float px1 = 1.4142135623730951f * xx * px0;
            float px2 = fmaf(xx, px1, -0.7071067811865476f * px0);
            float ey = __expf(-0.5f*(xy*xy));
            float py0 = 0.7511255444649425f * ey;
            float py1 = 1.4142135623730951f * xy * py0;
            float py2 = fmaf(xy, py1, -0.7071067811865476f * py0);
            float* hr = hA + lane*RS;
            hr[0]=px0*py0; hr[1]=px0*py1; hr[2]=px0*py2;
            hr[3]=px1*py0; hr[4]=px1*py1; hr[5]=px1*py2;
            hr[6]=px2*py0; hr[7]=px2*py1; hr[8]=px2*py2;
            hr[41]=0.f; hr[42]=0.f; hr[43]=0.f;
        }

        // ---- L1 (10->64): registers via readlane; write h1 to LDS ----
        #pragma unroll
        for (int r=0;r<12;r++){
            float xr = bcastf(xx, r);
            float yr = bcastf(xy, r);
            int   sr = __builtin_amdgcn_readlane(s_n, r);
            float a  = fmaf(xr, w1c0, b1r);
            a = fmaf(yr, w1c1, a);
            a += sr ? emb1 : emb0;
            h1[r*64 + lane] = __fdividef(a, 1.f + __expf(-a));
        }
        WFENCE();

        // ---- L2 (64->64): per-lane W2T row (LDS) x uniform-broadcast h (LDS) ----
        float acc[12];
        #pragma unroll
        for (int r=0;r<12;r++) acc[r] = b2r;
        #pragma unroll
        for (int i4=0;i4<16;i4++){
            float4 w4 = *(const float4*)(W2tl + lane*68 + i4*4);
            #pragma unroll
            for (int r=0;r<12;r++){
                float4 h4 = *(const float4*)(h1 + r*64 + i4*4);   // uniform addr
                acc[r]=fmaf(w4.x,h4.x,acc[r]); acc[r]=fmaf(w4.y,h4.y,acc[r]);
                acc[r]=fmaf(w4.z,h4.z,acc[r]); acc[r]=fmaf(w4.w,h4.w,acc[r]);
            }
        }
        WFENCE();          // all reads done before overwrite
        #pragma unroll
        for (int r=0;r<12;r++){
            float v = acc[r];
            h1[r*64 + lane] = __fdividef(v, 1.f + __expf(-v));
        }
        WFENCE();

        // ---- L3 (64->32): half-wave per element; W3T from LDS ----
        {
            int j2 = lane & 31, hf = lane >> 5;
            float a3[6];
            #pragma unroll
            for (int rr=0;rr<6;rr++) a3[rr] = b3r;
            #pragma unroll
            for (int i4=0;i4<16;i4++){
                float4 w4 = *(const float4*)(W3tl + j2*68 + i4*4);
                #pragma unroll
                for (int rr=0;rr<6;rr++){
                    float4 h4 = *(const float4*)(h1 + (hf*6+rr)*64 + i4*4);
                    a3[rr]=fmaf(w4.x,h4.x,a3[rr]); a3[rr]=fmaf(w4.y,h4.y,a3[rr]);
                    a3[rr]=fmaf(w4.z,h4.z,a3[rr]); a3[rr]=fmaf(w4.w,h4.w,a3[rr]);
                }
            }
            #pragma unroll
            for (int rr=0;rr<6;rr++) hA[(hf*6+rr)*RS + 9 + j2] = a3[rr];
        }
        WFENCE();

        // ---- h rows lane-distributed (lane = col) ----
        float hreg[12];
        #pragma unroll
        for (int r=0;r<12;r++) hreg[r] = hA[r*RS + le];
        WFENCE();

        // ---- bilinear + pfaffian (all-readlane matvec, full F row in regs) ----
        float total = 0.f;
        #pragma unroll 1
        for (int k = 0; k < KDET; ++k) {
            #pragma unroll 1
            for (int pass=0; pass<3; ++pass) {
                const float4* Fp = wsF + (size_t)(pass*4 + k)*(11*64) + lane;
                float4 fA=Fp[0],    fB=Fp[64],   fC=Fp[2*64], fD=Fp[3*64];
                float4 fE=Fp[4*64], fF=Fp[5*64], fG=Fp[6*64], fH=Fp[7*64];
                float4 fI=Fp[8*64], fJ=Fp[9*64], fK=Fp[10*64];
                const int dstb = (pass==2) ? 6 : 0;
                #pragma unroll
                for (int gg=0; gg<2; ++gg){
                    const unsigned dng = gg ? dn1 : dn0;
                    const unsigned mk  = pass ? dng : ((~dng) & 63u);
                    #pragma unroll
                    for (int m=0;m<6;m++){
                        if ((mk>>m)&1) {
                            const float hv = hreg[gg*6+m];
                            float a0, a1, a2, a3v;
                            a0  = fA.x * bcastf(hv,0);
                            a1  = fA.y * bcastf(hv,1);
                            a2  = fA.z * bcastf(hv,2);
                            a3v = fA.w * bcastf(hv,3);
                            a0  = fmaf(fB.x, bcastf(hv,4),  a0);
                            a1  = fmaf(fB.y, bcastf(hv,5),  a1);
                            a2  = fmaf(fB.z, bcastf(hv,6),  a2);
                            a3v = fmaf(fB.w, bcastf(hv,7),  a3v);
                            a0  = fmaf(fC.x, bcastf(hv,8),  a0);
                            a1  = fmaf(fC.y, bcastf(hv,9),  a1);
                            a2  = fmaf(fC.z, bcastf(hv,10), a2);
                            a3v = fmaf(fC.w, bcastf(hv,11), a3v);
                            a0  = fmaf(fD.x, bcastf(hv,12), a0);
                            a1  = fmaf(fD.y, bcastf(hv,13), a1);
                            a2  = fmaf(fD.z, bcastf(hv,14), a2);
                            a3v = fmaf(fD.w, bcastf(hv,15), a3v);
                            a0  = fmaf(fE.x, bcastf(hv,16), a0);
                            a1  = fmaf(fE.y, bcastf(hv,17), a1);
                            a2  = fmaf(fE.z, bcastf(hv,18), a2);
                            a3v = fmaf(fE.w, bcastf(hv,19), a3v);
                            a0  = fmaf(fF.x, bcastf(hv,20), a0);
                            a1  = fmaf(fF.y, bcastf(hv,21), a1);
                            a2  = fmaf(fF.z, bcastf(hv,22), a2);
                            a3v = fmaf(fF.w, bcastf(hv,23), a3v);
                            a0  = fmaf(fG.x, bcastf(hv,24), a0);
                            a1  = fmaf(fG.y, bcastf(hv,25), a1);
                            a2  = fmaf(fG.z, bcastf(hv,26), a2);
                            a3v = fmaf(fG.w, bcastf(hv,27), a3v);
                            a0  = fmaf(fH.x, bcastf(hv,28), a0);
                            a1  = fmaf(fH.y, bcastf(hv,29), a1);
                            a2  = fmaf(fH.z, bcastf(hv,30), a2);
                            a3v = fmaf(fH.w, bcastf(hv,31), a3v);
                            a0  = fmaf(fI.x, bcastf(hv,32), a0);
                            a1  = fmaf(fI.y, bcastf(hv,33), a1);
                            a2  = fmaf(fI.z, bcastf(hv,34), a2);
                            a3v = fmaf(fI.w, bcastf(hv,35), a3v);
                            a0  = fmaf(fJ.x, bcastf(hv,36), a0);
                            a1  = fmaf(fJ.y, bcastf(hv,37), a1);
                            a2  = fmaf(fJ.z, bcastf(hv,38), a2);
                            a3v = fmaf(fJ.w, bcastf(hv,39), a3v);
                            a0  = fmaf(fK.x, bcastf(hv,40), a0);
                            float t = (a0+a1)+(a2+a3v);
                            if (lane < RS)
                                t_s[(gg*12 + dstb + m)*RS + lane] = (lane < 41) ? t : 0.f;
                        }
                    }
                }
            }
            WFENCE();

            // ---- A[pair] for both elements: lanes (g*32+p), p<15 ----
            float av = 0.f;
            if (p < 15) {
                unsigned dng = g ? dn1 : dn0;
                int sn = (int)((dng>>pn)&1), sm = (int)((dng>>pm)&1);
                int hrow, trow; float sg;
                if (sn == sm)      { hrow = pn; trow = pm;     sg =  1.f; }
                else if (sn == 0)  { hrow = pn; trow = 6 + pm; sg =  1.f; }
                else               { hrow = pm; trow = 6 + pn; sg = -1.f; }
                const float4* hp = (const float4*)(hA  + (g*6  + hrow)*RS);
                const float4* tp = (const float4*)(t_s + (g*12 + trow)*RS);
                float a0=0.f,a1=0.f,a2=0.f,a3v=0.f;
                #pragma unroll
                for (int q=0;q<11;q++){
                    float4 hv = hp[q]; float4 tv = tp[q];
                    a0=fmaf(hv.x,tv.x,a0); a1=fmaf(hv.y,tv.y,a1);
                    a2=fmaf(hv.z,tv.z,a2); a3v=fmaf(hv.w,tv.w,a3v);
                }
                av = sg * ((a0+a1)+(a2+a3v));
            }
            int g32 = lane & 32;
            float q1 = __shfl(av, g32 + m1i);
            float q2 = __shfl(av, g32 + m2i);
            float q3 = __shfl(av, g32 + m3i);
            float term = 0.f;
            if (p < 15) { float pr = q1*q2*q3; term = (p & 1) ? -pr : pr; }
            term += __shfl_xor(term, 1);
            term += __shfl_xor(term, 2);
            term += __shfl_xor(term, 4);
            term += __shfl_xor(term, 8);
            total = fmaf(wreg[k], term, total);
            WFENCE();
        }

        if (p == 0) {
            int e = e0 + g;
            float sgn = (total > 0.f) ? 1.f : ((total < 0.f) ? -1.f : 1.f);
            out[e]         = sgn;
            out[B_TOT + e] = 0.5f * logf(fmaf(total, total, 1e-60f));
        }
        WFENCE();
    }
}

extern "C" void kernel_launch(void* const* d_in, const int* in_sizes, int n_in,
                              void* d_out, int out_size, void* d_ws, size_t ws_size,
                              hipStream_t stream)
{
    const float* x    = (const float*)d_in[0];
    const int*   spin = (const int*)  d_in[1];
    const float* se   = (const float*)d_in[2];
    const float* W1   = (const float*)d_in[3];
    const float* b1   = (const float*)d_in[4];
    const float* W2   = (const float*)d_in[5];
    const float* b2   = (const float*)d_in[6];
    const float* W3   = (const float*)d_in[7];
    const float* b3   = (const float*)d_in[8];
    const float* Phf  = (const float*)d_in[9];
    const float* dFud = (const float*)d_in[10];
    const float* dFuu = (const float*)d_in[11];
    const float* dFdd = (const float*)d_in[12];
    const float* w    = (const float*)d_in[13];
    float* out = (float*)d_out;
    float4* ws = (float4*)d_ws;

    hipLaunchKernelGGL(prep_F, dim3(33), dim3(256), 0, stream,
                       dFud, dFuu, dFdd, Phf, ws);
    hipLaunchKernelGGL(pfaff_main, dim3(2048), dim3(256), 0, stream,
                       x, spin, se, W1, b1, W2, b2, W3, b3, w, ws, out);
}

// Round 13
// 396.587 us; speedup vs baseline: 1.7669x; 1.2307x over previous
//
#include <hip/hip_runtime.h>

#define B_TOT 65536
#define RS 44            // padded row stride (floats) for h / t rows
#define KDET 4

// ---- LDS: block-shared weights + per-wave scratch (one __syncthreads at init)
#define OFF_W2T  0                   // 64*68 = 4352 (W2^T, rows padded to 68)
#define OFF_W3T  4352                // 32*68 = 2176
#define OFF_SC   6528                // 4 waves * 1584
#define SC_STRIDE 1584               // t_s [0,1056) (h1 time-shares [128,896)) | hA [1056,1584)
#define LDS_FLOATS (6528 + 4*1584)   // 12864 floats = 51456 B -> 3 blocks/CU

// workspace layout (float4 units): F only
#define WS_F   0                     // 12*11*64 = 8448 float4 = 135168 B

// pair enumeration p=0..14 : (n,m) lexicographic n<m
__device__ const int PN_TAB[15] = {0,0,0,0,0,1,1,1,1,2,2,2,3,3,4};
__device__ const int PM_TAB[15] = {1,2,3,4,5,2,3,4,5,3,4,5,4,5,5};
// matchings -> 3 pair indices; sign alternates +,-,+,...
__device__ const int M1_TAB[15] = {0,0,0,1,1,1,2,2,2,3,3,3,4,4,4};
__device__ const int M2_TAB[15] = {9,10,11,6,7,8,5,7,8,5,6,8,5,6,7};
__device__ const int M3_TAB[15] = {14,13,12,14,13,12,14,11,10,13,11,9,12,10,9};

__device__ __forceinline__ float bcastf(float v, int l) {
    return __int_as_float(__builtin_amdgcn_readlane(__float_as_int(v), l));
}
// wave-local LDS ordering only; vmcnt NOT drained (keeps F loads in flight)
#define WFENCE() asm volatile("s_waitcnt lgkmcnt(0)" ::: "memory")

// prep: F~ swizzled [sk][c][d] float4 (cols 4c..4c+3 of row d), rows/cols >=41 zero
__global__ void prep_F(const float* __restrict__ dFud, const float* __restrict__ dFuu,
                       const float* __restrict__ dFdd, const float* __restrict__ Phf,
                       float4* __restrict__ ws)
{
    int t = blockIdx.x * 256 + threadIdx.x;
    if (t >= 12*11*64) return;
    int d  = t & 63;
    int c  = (t >> 6) % 11;
    int sk = t / (11*64);
    int s = sk >> 2, k = sk & 3;
    const float* src = (s==0) ? dFuu : (s==1) ? dFdd : dFud;
    float v[4];
    #pragma unroll
    for (int j=0;j<4;j++){
        int e = 4*c + j;
        float r = 0.f;
        if (d < 41 && e < 41) {
            if (s < 2) r = 0.01f * (src[(k*41+d)*41+e] - src[(k*41+e)*41+d]);
            else     { r = 0.01f *  src[(k*41+d)*41+e]; if (k==0) r += Phf[d*41+e]; }
        }
        v[j] = r;
    }
    ws[WS_F + t] = make_float4(v[0],v[1],v[2],v[3]);
}

// (256,3): VGPR cap 85, 12 waves/CU; LDS 51.5KB -> 3 blocks/CU matches.
__global__ __launch_bounds__(256, 3)
void pfaff_main(const float* __restrict__ x, const int* __restrict__ spin,
                const float* __restrict__ se, const float* __restrict__ W1,
                const float* __restrict__ b1, const float* __restrict__ W2,
                const float* __restrict__ b2, const float* __restrict__ W3,
                const float* __restrict__ b3, const float* __restrict__ wdet,
                const float4* __restrict__ ws, float* __restrict__ out)
{
    __shared__ __align__(16) float lds[LDS_FLOATS];
    float* W2tl = lds + OFF_W2T;
    float* W3tl = lds + OFF_W3T;

    const int tid  = threadIdx.x;
    const int wave = tid >> 6, lane = tid & 63;

    // ---- stage W2^T / W3^T into LDS (pad-68 rows, pads zeroed) ----
    for (int idx = tid; idx < 64*68; idx += 256) {
        int j = idx / 68, i = idx - j*68;
        W2tl[idx] = (i < 64) ? W2[i*64 + j] : 0.f;
    }
    for (int idx = tid; idx < 32*68; idx += 256) {
        int j = idx / 68, i = idx - j*68;
        W3tl[idx] = (i < 64) ? W3[i*32 + j] : 0.f;
    }
    float* sc  = lds + OFF_SC + wave*SC_STRIDE;
    float* t_s = sc;            // [0,1056)
    float* h1  = sc + 128;      // [128,896) (time-shared with t_s)
    float* hA  = sc + 1056;     // [1056,1584)
    for (int i = lane; i < SC_STRIDE; i += 64) sc[i] = 0.f;
    __syncthreads();            // once; waves independent afterwards

    const float4* wsF = ws + WS_F;

    // ---- per-lane persistent preloads (from global; tiny, one-time) ----
    const float b1r = b1[lane];
    const float b2r = b2[lane];
    const float b3r = b3[lane & 31];
    const float w1c0 = W1[lane], w1c1 = W1[64 + lane];
    float emb0 = 0.f, emb1 = 0.f;
    #pragma unroll
    for (int j=0;j<8;j++){
        float wv = W1[(2+j)*64 + lane];
        emb0 = fmaf(wv, se[j],   emb0);
        emb1 = fmaf(wv, se[8+j], emb1);
    }
    int pn=0, pm=0, m1i=0, m2i=0, m3i=0;
    const int p = lane & 31, g = lane >> 5;
    if (p < 15) { pn=PN_TAB[p]; pm=PM_TAB[p];
                  m1i=M1_TAB[p]; m2i=M2_TAB[p]; m3i=M3_TAB[p]; }
    float wreg[4];
    #pragma unroll
    for (int k=0;k<4;k++) wreg[k] = wdet[k];

    const int ebase = ((int)blockIdx.x * 4 + wave) * 8;
    #pragma unroll 1
    for (int pi = 0; pi < 4; ++pi) {
        const int e0 = ebase + pi*2;

        // ---- P0: particle data for 2 elements; Phi -> hA rows ----
        int s_n = 0; float xx = 0.f, xy = 0.f;
        if (lane < 12) {
            int gg = lane >= 6;
            int eg = e0 + gg;
            int n  = lane - gg*6;
            float2 xv = *(const float2*)(x + (size_t)(eg*6 + n)*2);
            xx = xv.x; xy = xv.y;
            s_n = spin[eg*6 + n];
        }
        unsigned long long bal = __ballot(lane < 12 && s_n == 1);
        // masks live in SGPRs -> per-m conditions are scalar branches
        const unsigned dn0 = (unsigned)__builtin_amdgcn_readfirstlane((int)((unsigned)bal & 63u));
        const unsigned dn1 = (unsigned)__builtin_amdgcn_readfirstlane((int)((unsigned)(bal >> 6) & 63u));

        if (lane < 12) {
            float ex = __expf(-0.5f*(xx*xx));
            float px0 = 0.7511255444649425f * ex;
            float px1 = 1.4142135623730951f * xx * px0;
            float px2 = fmaf(xx, px1, -0.7071067811865476f * px0);
            float ey = __expf(-0.5f*(xy*xy));
            float py0 = 0.7511255444649425f * ey;
            float py1 = 1.4142135623730951f * xy * py0;
            float py2 = fmaf(xy, py1, -0.7071067811865476f * py0);
            float* hr = hA + lane*RS;
            hr[0]=px0*py0; hr[1]=px0*py1; hr[2]=px0*py2;
            hr[3]=px1*py0; hr[4]=px1*py1; hr[5]=px1*py2;
            hr[6]=px2*py0; hr[7]=px2*py1; hr[8]=px2*py2;
            hr[41]=0.f; hr[42]=0.f; hr[43]=0.f;
        }

        // ---- L1 (10->64): registers via readlane; write h1 to LDS ----
        #pragma unroll
        for (int r=0;r<12;r++){
            float xr = bcastf(xx, r);
            float yr = bcastf(xy, r);
            int   sr = __builtin_amdgcn_readlane(s_n, r);
            float a  = fmaf(xr, w1c0, b1r);
            a = fmaf(yr, w1c1, a);
            a += sr ? emb1 : emb0;
            h1[r*64 + lane] = __fdividef(a, 1.f + __expf(-a));
        }
        WFENCE();

        // ---- L2 (64->64): per-lane W2T row (LDS) x uniform-broadcast h (LDS) ----
        float acc[12];
        #pragma unroll
        for (int r=0;r<12;r++) acc[r] = b2r;
        #pragma unroll
        for (int i4=0;i4<16;i4++){
            float4 w4 = *(const float4*)(W2tl + lane*68 + i4*4);
            #pragma unroll
            for (int r=0;r<12;r++){
                float4 h4 = *(const float4*)(h1 + r*64 + i4*4);   // uniform addr
                acc[r]=fmaf(w4.x,h4.x,acc[r]); acc[r]=fmaf(w4.y,h4.y,acc[r]);
                acc[r]=fmaf(w4.z,h4.z,acc[r]); acc[r]=fmaf(w4.w,h4.w,acc[r]);
            }
        }
        WFENCE();          // all reads done before overwrite
        #pragma unroll
        for (int r=0;r<12;r++){
            float v = acc[r];
            h1[r*64 + lane] = __fdividef(v, 1.f + __expf(-v));
        }
        WFENCE();

        // ---- L3 (64->32): half-wave per element; W3T from LDS ----
        {
            int j2 = lane & 31, hf = lane >> 5;
            float a3[6];
            #pragma unroll
            for (int rr=0;rr<6;rr++) a3[rr] = b3r;
            #pragma unroll
            for (int i4=0;i4<16;i4++){
                float4 w4 = *(const float4*)(W3tl + j2*68 + i4*4);
                #pragma unroll
                for (int rr=0;rr<6;rr++){
                    float4 h4 = *(const float4*)(h1 + (hf*6+rr)*64 + i4*4);
                    a3[rr]=fmaf(w4.x,h4.x,a3[rr]); a3[rr]=fmaf(w4.y,h4.y,a3[rr]);
                    a3[rr]=fmaf(w4.z,h4.z,a3[rr]); a3[rr]=fmaf(w4.w,h4.w,a3[rr]);
                }
            }
            #pragma unroll
            for (int rr=0;rr<6;rr++) hA[(hf*6+rr)*RS + 9 + j2] = a3[rr];
        }
        WFENCE();

        // ---- bilinear + pfaffian: h via uniform ds_read_b128 broadcast only ----
        float total = 0.f;
        #pragma unroll 1
        for (int k = 0; k < KDET; ++k) {
            #pragma unroll 1
            for (int pass=0; pass<3; ++pass) {
                const float4* Fp = wsF + (size_t)(pass*4 + k)*(11*64) + lane;
                float4 fA=Fp[0],    fB=Fp[64],   fC=Fp[2*64], fD=Fp[3*64];
                float4 fE=Fp[4*64], fF=Fp[5*64], fG=Fp[6*64], fH=Fp[7*64];
                float4 fI=Fp[8*64], fJ=Fp[9*64], fK=Fp[10*64];
                const int dstb = (pass==2) ? 6 : 0;
                #pragma unroll
                for (int gg=0; gg<2; ++gg){
                    const unsigned dng = gg ? dn1 : dn0;
                    const unsigned mk  = pass ? dng : ((~dng) & 63u);
                    #pragma unroll
                    for (int m=0;m<6;m++){
                        if ((mk>>m)&1) {
                            const float* hm = hA + (gg*6+m)*RS;
                            float4 q;
                            float a0, a1, a2, a3v;
                            q = *(const float4*)(hm);
                            a0  = fA.x*q.x; a1 = fA.y*q.y;
                            a2  = fA.z*q.z; a3v= fA.w*q.w;
                            q = *(const float4*)(hm+4);
                            a0=fmaf(fB.x,q.x,a0); a1=fmaf(fB.y,q.y,a1);
                            a2=fmaf(fB.z,q.z,a2); a3v=fmaf(fB.w,q.w,a3v);
                            q = *(const float4*)(hm+8);
                            a0=fmaf(fC.x,q.x,a0); a1=fmaf(fC.y,q.y,a1);
                            a2=fmaf(fC.z,q.z,a2); a3v=fmaf(fC.w,q.w,a3v);
                            q = *(const float4*)(hm+12);
                            a0=fmaf(fD.x,q.x,a0); a1=fmaf(fD.y,q.y,a1);
                            a2=fmaf(fD.z,q.z,a2); a3v=fmaf(fD.w,q.w,a3v);
                            q = *(const float4*)(hm+16);
                            a0=fmaf(fE.x,q.x,a0); a1=fmaf(fE.y,q.y,a1);
                            a2=fmaf(fE.z,q.z,a2); a3v=fmaf(fE.w,q.w,a3v);
                            q = *(const float4*)(hm+20);
                            a0=fmaf(fF.x,q.x,a0); a1=fmaf(fF.y,q.y,a1);
                            a2=fmaf(fF.z,q.z,a2); a3v=fmaf(fF.w,q.w,a3v);
                            q = *(const float4*)(hm+24);
                            a0=fmaf(fG.x,q.x,a0); a1=fmaf(fG.y,q.y,a1);
                            a2=fmaf(fG.z,q.z,a2); a3v=fmaf(fG.w,q.w,a3v);
                            q = *(const float4*)(hm+28);
                            a0=fmaf(fH.x,q.x,a0); a1=fmaf(fH.y,q.y,a1);
                            a2=fmaf(fH.z,q.z,a2); a3v=fmaf(fH.w,q.w,a3v);
                            q = *(const float4*)(hm+32);
                            a0=fmaf(fI.x,q.x,a0); a1=fmaf(fI.y,q.y,a1);
                            a2=fmaf(fI.z,q.z,a2); a3v=fmaf(fI.w,q.w,a3v);
                            q = *(const float4*)(hm+36);
                            a0=fmaf(fJ.x,q.x,a0); a1=fmaf(fJ.y,q.y,a1);
                            a2=fmaf(fJ.z,q.z,a2); a3v=fmaf(fJ.w,q.w,a3v);
                            q = *(const float4*)(hm+40);
                            a0=fmaf(fK.x,q.x,a0); a1=fmaf(fK.y,q.y,a1);
                            a2=fmaf(fK.z,q.z,a2); a3v=fmaf(fK.w,q.w,a3v);
                            float t = (a0+a1)+(a2+a3v);
                            if (lane < RS)
                                t_s[(gg*12 + dstb + m)*RS + lane] = (lane < 41) ? t : 0.f;
                        }
                    }
                }
            }
            WFENCE();

            // ---- A[pair] for both elements: lanes (g*32+p), p<15 ----
            float av = 0.f;
            if (p < 15) {
                unsigned dng = g ? dn1 : dn0;
                int sn = (int)((dng>>pn)&1), sm = (int)((dng>>pm)&1);
                int hrow, trow; float sg;
                if (sn == sm)      { hrow = pn; trow = pm;     sg =  1.f; }
                else if (sn == 0)  { hrow = pn; trow = 6 + pm; sg =  1.f; }
                else               { hrow = pm; trow = 6 + pn; sg = -1.f; }
                const float4* hp = (const float4*)(hA  + (g*6  + hrow)*RS);
                const float4* tp = (const float4*)(t_s + (g*12 + trow)*RS);
                float a0=0.f,a1=0.f,a2=0.f,a3v=0.f;
                #pragma unroll
                for (int q=0;q<11;q++){
                    float4 hv = hp[q]; float4 tv = tp[q];
                    a0=fmaf(hv.x,tv.x,a0); a1=fmaf(hv.y,tv.y,a1);
                    a2=fmaf(hv.z,tv.z,a2); a3v=fmaf(hv.w,tv.w,a3v);
                }
                av = sg * ((a0+a1)+(a2+a3v));
            }
            int g32 = lane & 32;
            float q1 = __shfl(av, g32 + m1i);
            float q2 = __shfl(av, g32 + m2i);
            float q3 = __shfl(av, g32 + m3i);
            float term = 0.f;
            if (p < 15) { float pr = q1*q2*q3; term = (p & 1) ? -pr : pr; }
            term += __shfl_xor(term, 1);
            term += __shfl_xor(term, 2);
            term += __shfl_xor(term, 4);
            term += __shfl_xor(term, 8);
            total = fmaf(wreg[k], term, total);
            WFENCE();
        }

        if (p == 0) {
            int e = e0 + g;
            float sgn = (total > 0.f) ? 1.f : ((total < 0.f) ? -1.f : 1.f);
            out[e]         = sgn;
            out[B_TOT + e] = 0.5f * logf(fmaf(total, total, 1e-60f));
        }
        WFENCE();
    }
}

extern "C" void kernel_launch(void* const* d_in, const int* in_sizes, int n_in,
                              void* d_out, int out_size, void* d_ws, size_t ws_size,
                              hipStream_t stream)
{
    const float* x    = (const float*)d_in[0];
    const int*   spin = (const int*)  d_in[1];
    const float* se   = (const float*)d_in[2];
    const float* W1   = (const float*)d_in[3];
    const float* b1   = (const float*)d_in[4];
    const float* W2   = (const float*)d_in[5];
    const float* b2   = (const float*)d_in[6];
    const float* W3   = (const float*)d_in[7];
    const float* b3   = (const float*)d_in[8];
    const float* Phf  = (const float*)d_in[9];
    const float* dFud = (const float*)d_in[10];
    const float* dFuu = (const float*)d_in[11];
    const float* dFdd = (const float*)d_in[12];
    const float* w    = (const float*)d_in[13];
    float* out = (float*)d_out;
    float4* ws = (float4*)d_ws;

    hipLaunchKernelGGL(prep_F, dim3(33), dim3(256), 0, stream,
                       dFud, dFuu, dFdd, Phf, ws);
    hipLaunchKernelGGL(pfaff_main, dim3(2048), dim3(256), 0, stream,
                       x, spin, se, W1, b1, W2, b2, W3, b3, w, ws, out);
}